// Round 10
// baseline (458.502 us; speedup 1.0000x reference)
//
#include <hip/hip_runtime.h>

#define NPTS 2000
#define NBATCH 8
#define NC 256
#define NW 128
#define NK 10
#define NROWS (NBATCH * NPTS)
#define JPAD 2048
#define PL2 (JPAD * 32)            // f16 elems per (b,kc,hl) plane

typedef _Float16 f16x8 __attribute__((ext_vector_type(8)));
typedef _Float16 f16x4 __attribute__((ext_vector_type(4)));
typedef float f32x4 __attribute__((ext_vector_type(4)));

__device__ __forceinline__ float dot4(float4 a, float4 b) {
    return a.x*b.x + a.y*b.y + a.z*b.z + a.w*b.w;
}
__device__ __forceinline__ float4 relu4(float4 a) {
    return make_float4(fmaxf(a.x,0.f), fmaxf(a.y,0.f), fmaxf(a.z,0.f), fmaxf(a.w,0.f));
}
__device__ __forceinline__ float4 add4(float4 a, float4 b) {
    return make_float4(a.x+b.x, a.y+b.y, a.z+b.z, a.w+b.w);
}

__device__ __forceinline__ void ins10(float d, int j, float* vals, int* idxs) {
    if (d > vals[9]) {
        float v = d; int id = j;
        #pragma unroll
        for (int s = 0; s < 10; ++s) {
            if (v > vals[s]) {
                float tv = vals[s]; vals[s] = v; v = tv;
                int   ti = idxs[s]; idxs[s] = id; id = ti;
            }
        }
    }
}

// ---------------- Kernel P: transpose to planar f16 hi/lo + row norms ----------------
// xb: [b][kc(8)][hl(2)][2048 j][32 c] f16 (plain, no swizzle). Rows >= NPTS zero-filled.
__global__ __launch_bounds__(256) void k_prep(
    const float* __restrict__ x, _Float16* __restrict__ xb,
    float* __restrict__ xx)
{
    __shared__ float T[64][259];
    __shared__ float Pp[64][4];
    const int t  = threadIdx.x;
    const int b  = blockIdx.x >> 5;
    const int n0 = (blockIdx.x & 31) * 64;

    #pragma unroll
    for (int p = 0; p < 64; ++p) {
        const int idx = p*256 + t;
        const int c = idx >> 6, nl = idx & 63;
        T[nl][c] = x[((size_t)b*NC + c)*NPTS + min(n0 + nl, NPTS-1)];
    }
    __syncthreads();

    const int row = t & 63, q = t >> 6;
    const int gr  = n0 + row;
    const bool ok = gr < NPTS;
    float ss = 0.f;
    #pragma unroll
    for (int u = 0; u < 2; ++u) {
        const int kc = 2*q + u;
        const size_t bh = ((size_t)(b*8 + kc)*2    )*PL2 + (size_t)gr*32;
        const size_t bl = ((size_t)(b*8 + kc)*2 + 1)*PL2 + (size_t)gr*32;
        #pragma unroll
        for (int g = 0; g < 4; ++g) {
            f16x8 vh, vl;
            #pragma unroll
            for (int e = 0; e < 8; ++e) {
                const float f = ok ? T[row][kc*32 + g*8 + e] : 0.f;
                ss = fmaf(f, f, ss);
                const _Float16 h = (_Float16)f;
                vh[e] = h;
                vl[e] = (_Float16)(f - (float)h);
            }
            *(f16x8*)&xb[bh + g*8] = vh;
            *(f16x8*)&xb[bl + g*8] = vl;
        }
    }
    Pp[row][q] = ss;
    __syncthreads();
    if (t < 64 && n0 + t < NPTS)
        xx[(size_t)b*NPTS + n0 + t] = Pp[t][0] + Pp[t][1] + Pp[t][2] + Pp[t][3];
}

// ---------------- Kernel W: f32 -> f16 weight conversion ----------------
__global__ __launch_bounds__(256) void k_wprep(const float* __restrict__ a,
                                               _Float16* __restrict__ o, int n)
{
    const int i = (blockIdx.x*256 + threadIdx.x)*4;
    if (i < n) {
        const float4 v = *(const float4*)&a[i];
        f16x4 h = {(_Float16)v.x, (_Float16)v.y, (_Float16)v.z, (_Float16)v.w};
        *(f16x4*)&o[i] = h;
    }
}

// ---------------- Kernel A: row GEMM -> T1r / P / Q (unchanged) ----------------
__global__ __launch_bounds__(256) void k_rowgemm(
    const float* __restrict__ x,
    const float* __restrict__ tW1, const float* __restrict__ tb1,
    const float* __restrict__ sW1, const float* __restrict__ sb1,
    float* __restrict__ T1r, float* __restrict__ P, float* __restrict__ Q)
{
    __shared__ float Xs[32][34];
    __shared__ float Ws[32][132];
    const int t  = threadIdx.x;
    const int r0 = blockIdx.x * 32;
    const int sel = blockIdx.y;
    const int jq = t & 15,  iq = t >> 4;
    const int j0 = jq * 8,  i0 = iq * 2;

    float acc[2][8];
    #pragma unroll
    for (int a = 0; a < 2; ++a)
        #pragma unroll
        for (int q = 0; q < 8; ++q) acc[a][q] = 0.f;

    const int li = t & 31;
    const int lk = t >> 5;
    const int rl = r0 + li;
    const int lb = rl / NPTS, ln = rl % NPTS;

    for (int c0 = 0; c0 < NC; c0 += 32) {
        #pragma unroll
        for (int p = 0; p < 4; ++p) {
            int kk = lk + p * 8;
            Xs[kk][li] = x[((size_t)lb * NC + c0 + kk) * NPTS + ln];
        }
        #pragma unroll
        for (int jj = 0; jj < 16; ++jj) {
            int j = jj * 8 + lk;
            int c = c0 + li;
            float w;
            if (sel == 0)      w = tW1[j * NC + c];
            else if (sel == 1) w = sW1[j * (2*NC) + c];
            else               w = sW1[j * (2*NC) + NC + c];
            Ws[li][j] = w;
        }
        __syncthreads();
        #pragma unroll 8
        for (int kk = 0; kk < 32; ++kk) {
            const float2 xv = *(const float2*)&Xs[kk][i0];
            const float4 w0 = *(const float4*)&Ws[kk][j0];
            const float4 w1 = *(const float4*)&Ws[kk][j0 + 4];
            float w[8] = {w0.x,w0.y,w0.z,w0.w,w1.x,w1.y,w1.z,w1.w};
            #pragma unroll
            for (int q = 0; q < 8; ++q) {
                acc[0][q] = fmaf(xv.x, w[q], acc[0][q]);
                acc[1][q] = fmaf(xv.y, w[q], acc[1][q]);
            }
        }
        __syncthreads();
    }

    #pragma unroll
    for (int a = 0; a < 2; ++a) {
        const int r = r0 + i0 + a;
        float o[8];
        #pragma unroll
        for (int q = 0; q < 8; ++q) {
            float v = acc[a][q];
            if (sel == 0)      { v += tb1[j0+q]; v = fmaxf(v, 0.f); }
            else if (sel == 2) { v += sb1[j0+q]; }
            o[q] = v;
        }
        float* dst = (sel==0 ? T1r : (sel==1 ? P : Q)) + (size_t)r * NW + j0;
        *(float4*)dst       = make_float4(o[0],o[1],o[2],o[3]);
        *(float4*)(dst + 4) = make_float4(o[4],o[5],o[6],o[7]);
    }
}

// ---------------- Kernel B v8: barrier-free global->reg MFMA distance + reg top-10 ----------------
// Block = 4 waves x 16 i-rows. i-frags register-resident; j-tiles (16 j) read directly
// global->reg, coalesced 1KB/instr; all 4 waves share the tile via L1. xx staged to LDS
// once. NO barriers, NO LDS in the hot loop. Grid = 8b x 32ig x 3jh (672/672/656 j).
__global__ __launch_bounds__(256, 3) void k_topk(
    const _Float16* __restrict__ xb, const float* __restrict__ xx,
    float* __restrict__ pval, int* __restrict__ pidx)
{
    __shared__ __align__(16) char smem[20480];   // xxs (2.7KB) | merge overlay 20KB
    float* xxs = (float*)smem;

    const int t    = threadIdx.x;
    const int b    = blockIdx.x & 7;             // batch -> XCD
    const int ig   = (blockIdx.x >> 3) & 31;
    const int jh   = blockIdx.x >> 8;            // 0..2
    const int i0   = ig * 64;
    const int lane = t & 63;
    const int w    = t >> 6;
    const int lr   = lane & 15, rg = lane >> 4;
    const size_t bbase = (size_t)b * 16 * PL2;   // f16 elems
    const int jbase  = jh * 672;
    const int ntiles = (jh == 2) ? 41 : 42;

    // stage this third's xx into LDS (broadcast reads later)
    {
        const int ncnt = ntiles * 16;
        for (int idx = t; idx < ncnt; idx += 256)
            xxs[idx] = xx[(size_t)b*NPTS + jbase + idx];
    }

    // resident B-fragments: this wave's 16 i-rows, 8 kc x (hi,lo) = 64 VGPR
    f16x8 bh[8], bl[8];
    {
        const int i = min(i0 + w*16 + lr, NPTS - 1);
        #pragma unroll
        for (int kc = 0; kc < 8; ++kc) {
            const size_t ph = bbase + (size_t)(kc*2)*PL2 + (size_t)i*32 + rg*8;
            bh[kc] = *(const f16x8*)&xb[ph];
            bl[kc] = *(const f16x8*)&xb[ph + PL2];
        }
    }

    float vals[10]; int idxs[10];
    #pragma unroll
    for (int s = 0; s < 10; ++s) { vals[s] = -3.0e38f; idxs[s] = 0x7fffffff; }

    __syncthreads();   // xxs ready (only barrier before the merge phase)

    for (int jt = 0; jt < ntiles; ++jt) {
        const int j0 = jbase + jt*16;
        // A-fragment address: row (j0+lr), granule rg -> coalesced 1KB per (kc,hl)
        const size_t ja = (size_t)(j0 + lr)*32 + rg*8;

        f32x4 acc = {0.f,0.f,0.f,0.f};
        #pragma unroll
        for (int h = 0; h < 2; ++h) {
            f16x8 ah[4], al[4];
            #pragma unroll
            for (int k4 = 0; k4 < 4; ++k4) {
                const int kc = h*4 + k4;
                ah[k4] = *(const f16x8*)&xb[bbase + (size_t)(kc*2    )*PL2 + ja];
                al[k4] = *(const f16x8*)&xb[bbase + (size_t)(kc*2 + 1)*PL2 + ja];
            }
            #pragma unroll
            for (int k4 = 0; k4 < 4; ++k4) {
                const int kc = h*4 + k4;
                acc = __builtin_amdgcn_mfma_f32_16x16x32_f16(ah[k4], bh[kc], acc, 0,0,0);
                acc = __builtin_amdgcn_mfma_f32_16x16x32_f16(ah[k4], bl[kc], acc, 0,0,0);
                acc = __builtin_amdgcn_mfma_f32_16x16x32_f16(al[k4], bh[kc], acc, 0,0,0);
            }
        }

        // selection: lane's i-col = lr; j rows = j0 + rg*4 + q, ascending
        {
            const int jr = jt*16 + rg*4;
            const f32x4 xv = *(const f32x4*)&xxs[jr];
            const float d0 = 2.f*acc[0] - xv[0];
            const float d1 = 2.f*acc[1] - xv[1];
            const float d2 = 2.f*acc[2] - xv[2];
            const float d3 = 2.f*acc[3] - xv[3];
            const float mx = fmaxf(fmaxf(d0, d1), fmaxf(d2, d3));
            if (mx > vals[9]) {
                const int jg = j0 + rg*4;
                ins10(d0, jg,     vals, idxs);
                ins10(d1, jg + 1, vals, idxs);
                ins10(d2, jg + 2, vals, idxs);
                ins10(d3, jg + 3, vals, idxs);
            }
        }
    }

    // ---- in-block merge: 4 rg-lists per (w,lr) group ----
    __syncthreads();
    float* mval = (float*)smem;
    int*   midx = (int*)(smem + 10240);
    {
        const int g = w*16 + lr;
        #pragma unroll
        for (int s = 0; s < 10; ++s) {
            mval[(g*4 + rg)*10 + s] = vals[s];
            midx[(g*4 + rg)*10 + s] = idxs[s];
        }
    }
    __syncthreads();
    if (t < 128) {   // step 1: merge (pr, pr+2) -> pr for pr in {0,1} of each group
        const int g = t >> 1, pr = t & 1;
        float* va = &mval[(g*4 + pr)*10];     int* ia = &midx[(g*4 + pr)*10];
        const float* vb = &mval[(g*4 + pr + 2)*10]; const int* ib = &midx[(g*4 + pr + 2)*10];
        float ov[10]; int oi[10]; int pa = 0, pb = 0;
        #pragma unroll
        for (int s = 0; s < 10; ++s) {
            const float A = va[pa], Bv = vb[pb];
            const int  Ai = ia[pa], Bi = ib[pb];
            const bool ta = (A > Bv) || (A == Bv && Ai < Bi);
            ov[s] = ta ? A : Bv; oi[s] = ta ? Ai : Bi;
            pa += ta ? 1 : 0; pb += ta ? 0 : 1;
        }
        #pragma unroll
        for (int s = 0; s < 10; ++s) { va[s] = ov[s]; ia[s] = oi[s]; }
    }
    __syncthreads();
    if (t < 64) {    // step 2: final merge per group + write partial
        const int g = t;
        const int i = i0 + g;
        if (i < NPTS) {
            const float* va = &mval[(g*4 + 0)*10]; const int* ia = &midx[(g*4 + 0)*10];
            const float* vb = &mval[(g*4 + 1)*10]; const int* ib = &midx[(g*4 + 1)*10];
            float* ov = &pval[((size_t)(b*NPTS + i)*3 + jh)*10];
            int*   oi = &pidx[((size_t)(b*NPTS + i)*3 + jh)*10];
            int pa = 0, pb = 0;
            #pragma unroll
            for (int s = 0; s < 10; ++s) {
                const float A = va[pa], Bv = vb[pb];
                const int  Ai = ia[pa], Bi = ib[pb];
                const bool ta = (A > Bv) || (A == Bv && Ai < Bi);
                ov[s] = ta ? A : Bv; oi[s] = ta ? Ai : Bi;
                pa += ta ? 1 : 0; pb += ta ? 0 : 1;
            }
        }
    }
}

// ---------------- Kernel M: 3-way heads-merge of j-third partials ----------------
__global__ __launch_bounds__(256) void k_tkmerge(
    const float* __restrict__ pval, const int* __restrict__ pidx,
    int* __restrict__ tk)
{
    const int r = blockIdx.x*256 + threadIdx.x;
    if (r >= NROWS) return;
    const float* v  = &pval[(size_t)r*30];
    const int*   ix = &pidx[(size_t)r*30];
    const int base = (r / NPTS) * NPTS;
    int* op = &tk[(size_t)r*NK];
    int p0 = 0, p1 = 0, p2 = 0;
    #pragma unroll
    for (int s = 0; s < NK; ++s) {
        float bv = -3.4e38f; int bi = 0x7fffffff; int bl = 0;
        {
            const float vv = v[p0];       const int ii = ix[p0];
            if (vv > bv || (vv == bv && ii < bi)) { bv = vv; bi = ii; bl = 0; }
        }
        {
            const float vv = v[10 + p1];  const int ii = ix[10 + p1];
            if (vv > bv || (vv == bv && ii < bi)) { bv = vv; bi = ii; bl = 1; }
        }
        {
            const float vv = v[20 + p2];  const int ii = ix[20 + p2];
            if (vv > bv || (vv == bv && ii < bi)) { bv = vv; bi = ii; bl = 2; }
        }
        p0 += (bl == 0); p1 += (bl == 1); p2 += (bl == 2);
        op[s] = base + bi;
    }
}

// ---------------- Kernel D: fused tail (MFMA phase 2, unchanged) ----------------
#define AST 136
__global__ __launch_bounds__(256, 2) void k_fused(
    const float* __restrict__ x,
    const int* __restrict__ nb, const int* __restrict__ tk,
    const float* __restrict__ T1r, const float* __restrict__ P, const float* __restrict__ Q,
    const float* __restrict__ tW2, const float* __restrict__ tb2,
    const float* __restrict__ sW2, const float* __restrict__ sb2,
    const _Float16* __restrict__ wt3h, const _Float16* __restrict__ ws3h,
    const float* __restrict__ tb3, const float* __restrict__ sb3,
    float* __restrict__ out)
{
    __shared__ __align__(16) _Float16 A16[144*AST];
    __shared__ float Ssm[8][260];
    __shared__ float Zr[8][260];

    const int t  = threadIdx.x;
    const int r0 = blockIdx.x * 8;
    const int bb = r0 / NPTS;
    const int n0 = r0 % NPTS;

    {
        const float4 z4 = make_float4(0.f,0.f,0.f,0.f);
        float4* p4 = (float4*)A16;
        #pragma unroll
        for (int i = 0; i < 10; ++i) {
            const int idx = t + i*256;
            if (idx < 2448) p4[idx] = z4;
        }
    }
    __syncthreads();

    {
        const int o    = t & 127;
        const int half = t >> 7;
        const int g4   = o & ~3;

        const float4 f0 = *(const float4*)&tW2[o*12];
        const float4 f1 = *(const float4*)&tW2[o*12 + 4];
        const float4 f2 = *(const float4*)&tW2[o*12 + 8];
        const float4 wt0 = make_float4(f0.x, f0.w, f1.z, f2.y);
        const float4 wt1 = make_float4(f0.y, f1.x, f1.w, f2.z);
        const float4 wt2 = make_float4(f0.z, f1.y, f2.x, f2.w);
        const float4 wsw = *(const float4*)&sW2[o*4];
        const float tb2o = tb2[o], sb2o = sb2[o];

        #pragma unroll
        for (int ptl = 0; ptl < 4; ++ptl) {
            const int pt = half*4 + ptl;
            const int r  = r0 + pt;
            const int nb0 = nb[r*3+0], nb1 = nb[r*3+1], nb2 = nb[r*3+2];
            int ki[NK];
            #pragma unroll
            for (int k = 0; k < NK; ++k) ki[k] = tk[r*NK + k];
            const float4 h0 = *(const float4*)&T1r[(size_t)nb0*NW + g4];
            const float4 h1 = *(const float4*)&T1r[(size_t)nb1*NW + g4];
            const float4 h2 = *(const float4*)&T1r[(size_t)nb2*NW + g4];
            const float4 qf = *(const float4*)&Q[(size_t)r*NW + g4];
            float4 pf[NK];
            #pragma unroll
            for (int k = 0; k < NK; ++k) pf[k] = *(const float4*)&P[(size_t)ki[k]*NW + g4];

            const float z = tb2o + dot4(wt0,h0) + dot4(wt1,h1) + dot4(wt2,h2);
            A16[(128 + pt)*AST + o] = (_Float16)fmaxf(z, 0.f);
            #pragma unroll
            for (int k = 0; k < NK; ++k) {
                const float4 g1 = relu4(add4(pf[k], qf));
                A16[(pt*16 + k)*AST + o] = (_Float16)fmaxf(dot4(wsw, g1) + sb2o, 0.f);
            }
        }
    }
    __syncthreads();

    const int lane = t & 63, w = t >> 6;
    const int lr = lane & 15, lg = lane >> 4;
    const int n0w = w * 64;

    f32x4 accG[8][4] = {};
    f32x4 accZ[4] = {};

    #pragma unroll
    for (int kt = 0; kt < 4; ++kt) {
        const int ko = kt*32 + lg*8;
        f16x8 bs[4], bt[4];
        #pragma unroll
        for (int nt = 0; nt < 4; ++nt) {
            const int n = n0w + nt*16 + lr;
            bs[nt] = *(const f16x8*)&ws3h[n*NW + ko];
            bt[nt] = *(const f16x8*)&wt3h[n*NW + ko];
        }
        #pragma unroll
        for (int mt = 0; mt < 8; ++mt) {
            const f16x8 a = *(const f16x8*)&A16[(mt*16 + lr)*AST + ko];
            #pragma unroll
            for (int nt = 0; nt < 4; ++nt)
                accG[mt][nt] = __builtin_amdgcn_mfma_f32_16x16x32_f16(a, bs[nt], accG[mt][nt], 0,0,0);
        }
        const f16x8 az = *(const f16x8*)&A16[(128 + lr)*AST + ko];
        #pragma unroll
        for (int nt = 0; nt < 4; ++nt)
            accZ[nt] = __builtin_amdgcn_mfma_f32_16x16x32_f16(az, bt[nt], accZ[nt], 0,0,0);
    }

    const int rg = lg;
    #pragma unroll
    for (int mt = 0; mt < 8; ++mt) {
        #pragma unroll
        for (int nt = 0; nt < 4; ++nt) {
            float v;
            if (rg < 2)       v = fmaxf(fmaxf(accG[mt][nt][0], accG[mt][nt][1]),
                                        fmaxf(accG[mt][nt][2], accG[mt][nt][3]));
            else if (rg == 2) v = fmaxf(accG[mt][nt][0], accG[mt][nt][1]);
            else              v = -3.0e38f;
            v = fmaxf(v, __shfl_xor(v, 16));
            v = fmaxf(v, __shfl_xor(v, 32));
            if (lane < 16) Ssm[mt][n0w + nt*16 + lane] = v;
        }
    }
    #pragma unroll
    for (int nt = 0; nt < 4; ++nt) {
        #pragma unroll
        for (int q = 0; q < 4; ++q) {
            if (rg < 2) Zr[rg*4 + q][n0w + nt*16 + lr] = accZ[nt][q];
        }
    }
    __syncthreads();

    {
        const int c = t;
        const float tb = tb3[c], sb = sb3[c];
        const size_t go = ((size_t)bb*NC + c)*NPTS + n0;
        const float4 xv0 = *(const float4*)&x[go];
        const float4 xv1 = *(const float4*)&x[go + 4];
        const float xr[8] = {xv0.x,xv0.y,xv0.z,xv0.w, xv1.x,xv1.y,xv1.z,xv1.w};
        float ov[8];
        #pragma unroll
        for (int p = 0; p < 8; ++p)
            ov[p] = fmaxf(Zr[p][c] + tb + Ssm[p][c] + sb + xr[p], 0.f);
        *(float4*)&out[go]     = make_float4(ov[0],ov[1],ov[2],ov[3]);
        *(float4*)&out[go + 4] = make_float4(ov[4],ov[5],ov[6],ov[7]);
    }
}

extern "C" void kernel_launch(void* const* d_in, const int* in_sizes, int n_in,
                              void* d_out, int out_size, void* d_ws, size_t ws_size,
                              hipStream_t stream) {
    (void)in_sizes; (void)n_in; (void)out_size; (void)ws_size;
    const float* x   = (const float*)d_in[0];
    const int*   nb  = (const int*)d_in[2];
    const float* tW1 = (const float*)d_in[3];
    const float* tb1 = (const float*)d_in[4];
    const float* tW2 = (const float*)d_in[5];
    const float* tb2 = (const float*)d_in[6];
    const float* tW3 = (const float*)d_in[7];
    const float* tb3 = (const float*)d_in[8];
    const float* sW1 = (const float*)d_in[9];
    const float* sb1 = (const float*)d_in[10];
    const float* sW2 = (const float*)d_in[11];
    const float* sb2 = (const float*)d_in[12];
    const float* sW3 = (const float*)d_in[13];
    const float* sb3 = (const float*)d_in[14];
    float* out = (float*)d_out;

    float* ws  = (float*)d_ws;
    float* T1r  = ws;                       // 2,048,000 f32
    float* P    = ws + 2048000;             // 2,048,000 f32
    float* Q    = ws + 4096000;             // 2,048,000 f32
    float* xxp  = ws + 6144000;             // 16,000 f32
    int*   tk   = (int*)(ws + 6160000);     // 160,000 int
    float* pval = ws + 6320000;             // 480,000 f32
    int*   pidx = (int*)(ws + 6800000);     // 480,000 int
    _Float16* xb   = (_Float16*)(ws + 7280000);   // 8,388,608 f16
    _Float16* wt3h = xb + (size_t)NBATCH * 16 * PL2;
    _Float16* ws3h = wt3h + NC * NW;

    k_prep<<<NBATCH * 32, 256, 0, stream>>>(x, xb, xxp);
    k_wprep<<<32, 256, 0, stream>>>(tW3, wt3h, NC * NW);
    k_wprep<<<32, 256, 0, stream>>>(sW3, ws3h, NC * NW);
    k_rowgemm<<<dim3(NROWS / 32, 3), 256, 0, stream>>>(x, tW1, tb1, sW1, sb1, T1r, P, Q);
    k_topk<<<768, 256, 0, stream>>>(xb, xxp, pval, pidx);
    k_tkmerge<<<(NROWS + 255) / 256, 256, 0, stream>>>(pval, pidx, tk);
    k_fused<<<NROWS / 8, 256, 0, stream>>>(x, nb, tk, T1r, P, Q,
                                           tW2, tb2, sW2, sb2, wt3h, ws3h, tb3, sb3, out);
}

// Round 11
// 392.731 us; speedup vs baseline: 1.1675x; 1.1675x over previous
//
#include <hip/hip_runtime.h>

#define NPTS 2000
#define NBATCH 8
#define NC 256
#define NW 128
#define NK 10
#define NROWS (NBATCH * NPTS)
#define JPAD 2048

typedef _Float16 f16x8 __attribute__((ext_vector_type(8)));
typedef _Float16 f16x4 __attribute__((ext_vector_type(4)));
typedef float f32x4 __attribute__((ext_vector_type(4)));

__device__ __forceinline__ float dot4(float4 a, float4 b) {
    return a.x*b.x + a.y*b.y + a.z*b.z + a.w*b.w;
}
__device__ __forceinline__ float4 relu4(float4 a) {
    return make_float4(fmaxf(a.x,0.f), fmaxf(a.y,0.f), fmaxf(a.z,0.f), fmaxf(a.w,0.f));
}
__device__ __forceinline__ float4 add4(float4 a, float4 b) {
    return make_float4(a.x+b.x, a.y+b.y, a.z+b.z, a.w+b.w);
}

__device__ __forceinline__ void ins10(float d, int j, float* vals, int* idxs) {
    if (d > vals[9]) {
        float v = d; int id = j;
        #pragma unroll
        for (int s = 0; s < 10; ++s) {
            if (v > vals[s]) {
                float tv = vals[s]; vals[s] = v; v = tv;
                int   ti = idxs[s]; idxs[s] = id; id = ti;
            }
        }
    }
}

// ---------------- Kernel P: transpose to interleaved f16 hi/lo + row norms ----------------
// xb: [b][j(2048)][plane p=kc*2+hl (16)][32 c] f16 — one row = contiguous 1 KB.
// Rows >= NPTS zero-filled.
__global__ __launch_bounds__(256) void k_prep(
    const float* __restrict__ x, _Float16* __restrict__ xb,
    float* __restrict__ xx)
{
    __shared__ float T[64][259];
    __shared__ float Pp[64][4];
    const int t  = threadIdx.x;
    const int b  = blockIdx.x >> 5;
    const int n0 = (blockIdx.x & 31) * 64;

    #pragma unroll
    for (int p = 0; p < 64; ++p) {
        const int idx = p*256 + t;
        const int c = idx >> 6, nl = idx & 63;
        T[nl][c] = x[((size_t)b*NC + c)*NPTS + min(n0 + nl, NPTS-1)];
    }
    __syncthreads();

    const int row = t & 63, q = t >> 6;   // q -> kc planes 2q, 2q+1
    const int gr  = n0 + row;
    const bool ok = gr < NPTS;
    const size_t rb = ((size_t)b*JPAD + gr) * 512;   // f16 offset of row
    float ss = 0.f;
    #pragma unroll
    for (int u = 0; u < 2; ++u) {
        const int kc = 2*q + u;
        #pragma unroll
        for (int g = 0; g < 4; ++g) {
            f16x8 vh, vl;
            #pragma unroll
            for (int e = 0; e < 8; ++e) {
                const float f = ok ? T[row][kc*32 + g*8 + e] : 0.f;
                ss = fmaf(f, f, ss);
                const _Float16 h = (_Float16)f;
                vh[e] = h;
                vl[e] = (_Float16)(f - (float)h);
            }
            *(f16x8*)&xb[rb + (kc*2    )*32 + g*8] = vh;
            *(f16x8*)&xb[rb + (kc*2 + 1)*32 + g*8] = vl;
        }
    }
    Pp[row][q] = ss;
    __syncthreads();
    if (t < 64 && n0 + t < NPTS)
        xx[(size_t)b*NPTS + n0 + t] = Pp[t][0] + Pp[t][1] + Pp[t][2] + Pp[t][3];
}

// ---------------- Kernel W: f32 -> f16 weight conversion (tW3/sW3) ----------------
__global__ __launch_bounds__(256) void k_wprep(const float* __restrict__ a,
                                               _Float16* __restrict__ o, int n)
{
    const int i = (blockIdx.x*256 + threadIdx.x)*4;
    if (i < n) {
        const float4 v = *(const float4*)&a[i];
        f16x4 h = {(_Float16)v.x, (_Float16)v.y, (_Float16)v.z, (_Float16)v.w};
        *(f16x4*)&o[i] = h;
    }
}

// ---------------- Kernel Wc: build whcat[384][256] f16 = [tW1; sW1_A; sW1_B] ----------------
__global__ __launch_bounds__(256) void k_wcat(
    const float* __restrict__ tW1, const float* __restrict__ sW1,
    _Float16* __restrict__ whcat)
{
    const int idx = blockIdx.x*256 + threadIdx.x;   // 384*256
    const int n = idx >> 8, k = idx & 255;
    float v;
    if (n < 128)      v = tW1[n*256 + k];
    else if (n < 256) v = sW1[(n-128)*512 + k];
    else              v = sW1[(n-256)*512 + 256 + k];
    whcat[idx] = (_Float16)v;
}

// ---------------- Kernel A v2: MFMA row GEMM -> T1r / P / Q ----------------
// Block = one 16-row tile (4 waves, each covers 6 n-tiles of 16). 2-pass (xh+xl)*Wh.
__global__ __launch_bounds__(256) void k_rowmm(
    const _Float16* __restrict__ xb, const _Float16* __restrict__ whcat,
    const float* __restrict__ tb1, const float* __restrict__ sb1,
    float* __restrict__ T1r, float* __restrict__ P, float* __restrict__ Q)
{
    const int t = threadIdx.x, lane = t & 63, w = t >> 6;
    const int lr = lane & 15, rg = lane >> 4;
    const int r0 = blockIdx.x * 16;
    const int b  = r0 / NPTS, jr = r0 % NPTS;   // 2000 % 16 == 0 -> tile in one batch

    f16x8 ah[8], al[8];
    const size_t rb = ((size_t)b*JPAD + jr + lr) * 512 + rg*8;
    #pragma unroll
    for (int kc = 0; kc < 8; ++kc) {
        ah[kc] = *(const f16x8*)&xb[rb + kc*64];
        al[kc] = *(const f16x8*)&xb[rb + kc*64 + 32];
    }

    #pragma unroll
    for (int nt = 0; nt < 6; ++nt) {
        const int n0 = (w*6 + nt) * 16;
        f32x4 acc = {0.f,0.f,0.f,0.f};
        #pragma unroll
        for (int kc = 0; kc < 8; ++kc) {
            const f16x8 bw = *(const f16x8*)&whcat[(size_t)(n0 + lr)*256 + kc*32 + rg*8];
            acc = __builtin_amdgcn_mfma_f32_16x16x32_f16(ah[kc], bw, acc, 0,0,0);
            acc = __builtin_amdgcn_mfma_f32_16x16x32_f16(al[kc], bw, acc, 0,0,0);
        }
        const int n = n0 + lr;
        float bias; bool dorelu; float* dst;
        if (n < 128)      { bias = tb1[n];     dorelu = true;  dst = T1r + (size_t)r0*NW + n; }
        else if (n < 256) { bias = 0.f;        dorelu = false; dst = P   + (size_t)r0*NW + (n-128); }
        else              { bias = sb1[n-256]; dorelu = false; dst = Q   + (size_t)r0*NW + (n-256); }
        #pragma unroll
        for (int q = 0; q < 4; ++q) {
            float v = acc[q] + bias;
            if (dorelu) v = fmaxf(v, 0.f);
            dst[(size_t)(rg*4 + q)*NW] = v;
        }
    }
}

// ---------------- Kernel B v9: interleaved-layout pipelined MFMA distance + reg top-10 ----------------
// Block = 4 waves x 16 i-rows (reg-resident). j streamed global->reg, one contiguous
// 16KB per 16-j tile, register double-buffered (RA/RB) one tile ahead. No barriers in
// the hot loop. Grid = 8b x 32ig x 2jh = 512 (2 blocks/CU).
__global__ __launch_bounds__(256, 2) void k_topk(
    const _Float16* __restrict__ xb, const float* __restrict__ xx,
    float* __restrict__ pval, int* __restrict__ pidx)
{
    __shared__ __align__(16) char smem[20480];   // xxs 4KB | merge overlay 20KB
    float* xxs = (float*)smem;

    const int t    = threadIdx.x;
    const int b    = blockIdx.x & 7;             // batch -> XCD
    const int ig   = (blockIdx.x >> 3) & 31;
    const int jh   = blockIdx.x >> 8;            // 0..1
    const int i0   = ig * 64;
    const int lane = t & 63;
    const int w    = t >> 6;
    const int lr   = lane & 15, rg = lane >> 4;
    const size_t bj = (size_t)b * JPAD;
    const int tile0  = jh * 63;
    const int ntiles = jh ? 62 : 63;             // 125 tiles cover j 0..1999 exactly

    {   // stage this half's xx
        const int cnt = ntiles * 16;
        for (int idx = t; idx < cnt; idx += 256)
            xxs[idx] = xx[(size_t)b*NPTS + tile0*16 + idx];
    }

    // resident B-fragments: this wave's 16 i-rows, 8 kc x (hi,lo)
    f16x8 bh[8], bl[8];
    {
        const int i = min(i0 + w*16 + lr, NPTS - 1);
        const size_t rb = (bj + i) * 512 + rg*8;
        #pragma unroll
        for (int kc = 0; kc < 8; ++kc) {
            bh[kc] = *(const f16x8*)&xb[rb + kc*64];
            bl[kc] = *(const f16x8*)&xb[rb + kc*64 + 32];
        }
    }

    float vals[10]; int idxs[10];
    #pragma unroll
    for (int s = 0; s < 10; ++s) { vals[s] = -3.0e38f; idxs[s] = 0x7fffffff; }

    __syncthreads();   // xxs ready

    f16x8 RA[16], RB[16];
    const size_t lbase = (bj + lr) * 512 + rg*8;

#define LOADT(R, tt) { \
    const size_t a_ = lbase + (size_t)(tile0 + (tt)) * 8192; \
    _Pragma("unroll") \
    for (int p = 0; p < 16; ++p) R[p] = *(const f16x8*)&xb[a_ + p*32]; }

#define COMPUTE(R, tt) { \
    f32x4 acc = {0.f,0.f,0.f,0.f}; \
    _Pragma("unroll") \
    for (int kc = 0; kc < 8; ++kc) { \
        acc = __builtin_amdgcn_mfma_f32_16x16x32_f16(R[kc*2],   bh[kc], acc, 0,0,0); \
        acc = __builtin_amdgcn_mfma_f32_16x16x32_f16(R[kc*2],   bl[kc], acc, 0,0,0); \
        acc = __builtin_amdgcn_mfma_f32_16x16x32_f16(R[kc*2+1], bh[kc], acc, 0,0,0); \
    } \
    const int jr_ = (tt)*16 + rg*4; \
    const f32x4 xv_ = *(const f32x4*)&xxs[jr_]; \
    const float d0_ = 2.f*acc[0] - xv_[0]; \
    const float d1_ = 2.f*acc[1] - xv_[1]; \
    const float d2_ = 2.f*acc[2] - xv_[2]; \
    const float d3_ = 2.f*acc[3] - xv_[3]; \
    if (fmaxf(fmaxf(d0_,d1_), fmaxf(d2_,d3_)) > vals[9]) { \
        const int jg_ = (tile0 + (tt))*16 + rg*4; \
        ins10(d0_, jg_,     vals, idxs); \
        ins10(d1_, jg_ + 1, vals, idxs); \
        ins10(d2_, jg_ + 2, vals, idxs); \
        ins10(d3_, jg_ + 3, vals, idxs); } }

    LOADT(RA, 0)
    int jt = 0;
    while (jt + 2 <= ntiles) {
        LOADT(RB, jt + 1)
        COMPUTE(RA, jt)
        if (jt + 2 < ntiles) LOADT(RA, jt + 2)
        COMPUTE(RB, jt + 1)
        jt += 2;
    }
    if (jt < ntiles) COMPUTE(RA, jt)

#undef LOADT
#undef COMPUTE

    // ---- in-block merge: 4 rg-lists per (w,lr) group ----
    __syncthreads();
    float* mval = (float*)smem;
    int*   midx = (int*)(smem + 10240);
    {
        const int g = w*16 + lr;
        #pragma unroll
        for (int s = 0; s < 10; ++s) {
            mval[(g*4 + rg)*10 + s] = vals[s];
            midx[(g*4 + rg)*10 + s] = idxs[s];
        }
    }
    __syncthreads();
    if (t < 128) {   // step 1: merge (pr, pr+2) -> pr
        const int g = t >> 1, pr = t & 1;
        float* va = &mval[(g*4 + pr)*10];     int* ia = &midx[(g*4 + pr)*10];
        const float* vb = &mval[(g*4 + pr + 2)*10]; const int* ib = &midx[(g*4 + pr + 2)*10];
        float ov[10]; int oi[10]; int pa = 0, pb = 0;
        #pragma unroll
        for (int s = 0; s < 10; ++s) {
            const float A = va[pa], Bv = vb[pb];
            const int  Ai = ia[pa], Bi = ib[pb];
            const bool ta = (A > Bv) || (A == Bv && Ai < Bi);
            ov[s] = ta ? A : Bv; oi[s] = ta ? Ai : Bi;
            pa += ta ? 1 : 0; pb += ta ? 0 : 1;
        }
        #pragma unroll
        for (int s = 0; s < 10; ++s) { va[s] = ov[s]; ia[s] = oi[s]; }
    }
    __syncthreads();
    if (t < 64) {    // step 2: final merge + write partial
        const int g = t;
        const int i = i0 + g;
        if (i < NPTS) {
            const float* va = &mval[(g*4 + 0)*10]; const int* ia = &midx[(g*4 + 0)*10];
            const float* vb = &mval[(g*4 + 1)*10]; const int* ib = &midx[(g*4 + 1)*10];
            float* ov = &pval[((size_t)(b*NPTS + i)*2 + jh)*10];
            int*   oi = &pidx[((size_t)(b*NPTS + i)*2 + jh)*10];
            int pa = 0, pb = 0;
            #pragma unroll
            for (int s = 0; s < 10; ++s) {
                const float A = va[pa], Bv = vb[pb];
                const int  Ai = ia[pa], Bi = ib[pb];
                const bool ta = (A > Bv) || (A == Bv && Ai < Bi);
                ov[s] = ta ? A : Bv; oi[s] = ta ? Ai : Bi;
                pa += ta ? 1 : 0; pb += ta ? 0 : 1;
            }
        }
    }
}

// ---------------- Kernel M: merge the two j-half partial lists ----------------
__global__ __launch_bounds__(256) void k_tkmerge(
    const float* __restrict__ pval, const int* __restrict__ pidx,
    int* __restrict__ tk)
{
    const int r = blockIdx.x*256 + threadIdx.x;
    if (r >= NROWS) return;
    const float* va = &pval[(size_t)r*20];
    const int*   ia = &pidx[(size_t)r*20];
    const float* vb = va + 10;
    const int*   ib = ia + 10;
    const int base = (r / NPTS) * NPTS;
    int* op = &tk[(size_t)r*NK];
    int pa = 0, pb = 0;
    #pragma unroll
    for (int s = 0; s < NK; ++s) {
        const float A = va[pa], Bv = vb[pb];
        const int  Ai = ia[pa], Bi = ib[pb];
        const bool ta = (A > Bv) || (A == Bv && Ai < Bi);
        op[s] = base + (ta ? Ai : Bi);
        pa += ta ? 1 : 0; pb += ta ? 0 : 1;
    }
}

// ---------------- Kernel D: fused tail (MFMA phase 2, unchanged) ----------------
#define AST 136
__global__ __launch_bounds__(256, 2) void k_fused(
    const float* __restrict__ x,
    const int* __restrict__ nb, const int* __restrict__ tk,
    const float* __restrict__ T1r, const float* __restrict__ P, const float* __restrict__ Q,
    const float* __restrict__ tW2, const float* __restrict__ tb2,
    const float* __restrict__ sW2, const float* __restrict__ sb2,
    const _Float16* __restrict__ wt3h, const _Float16* __restrict__ ws3h,
    const float* __restrict__ tb3, const float* __restrict__ sb3,
    float* __restrict__ out)
{
    __shared__ __align__(16) _Float16 A16[144*AST];
    __shared__ float Ssm[8][260];
    __shared__ float Zr[8][260];

    const int t  = threadIdx.x;
    const int r0 = blockIdx.x * 8;
    const int bb = r0 / NPTS;
    const int n0 = r0 % NPTS;

    {
        const float4 z4 = make_float4(0.f,0.f,0.f,0.f);
        float4* p4 = (float4*)A16;
        #pragma unroll
        for (int i = 0; i < 10; ++i) {
            const int idx = t + i*256;
            if (idx < 2448) p4[idx] = z4;
        }
    }
    __syncthreads();

    {
        const int o    = t & 127;
        const int half = t >> 7;
        const int g4   = o & ~3;

        const float4 f0 = *(const float4*)&tW2[o*12];
        const float4 f1 = *(const float4*)&tW2[o*12 + 4];
        const float4 f2 = *(const float4*)&tW2[o*12 + 8];
        const float4 wt0 = make_float4(f0.x, f0.w, f1.z, f2.y);
        const float4 wt1 = make_float4(f0.y, f1.x, f1.w, f2.z);
        const float4 wt2 = make_float4(f0.z, f1.y, f2.x, f2.w);
        const float4 wsw = *(const float4*)&sW2[o*4];
        const float tb2o = tb2[o], sb2o = sb2[o];

        #pragma unroll
        for (int ptl = 0; ptl < 4; ++ptl) {
            const int pt = half*4 + ptl;
            const int r  = r0 + pt;
            const int nb0 = nb[r*3+0], nb1 = nb[r*3+1], nb2 = nb[r*3+2];
            int ki[NK];
            #pragma unroll
            for (int k = 0; k < NK; ++k) ki[k] = tk[r*NK + k];
            const float4 h0 = *(const float4*)&T1r[(size_t)nb0*NW + g4];
            const float4 h1 = *(const float4*)&T1r[(size_t)nb1*NW + g4];
            const float4 h2 = *(const float4*)&T1r[(size_t)nb2*NW + g4];
            const float4 qf = *(const float4*)&Q[(size_t)r*NW + g4];
            float4 pf[NK];
            #pragma unroll
            for (int k = 0; k < NK; ++k) pf[k] = *(const float4*)&P[(size_t)ki[k]*NW + g4];

            const float z = tb2o + dot4(wt0,h0) + dot4(wt1,h1) + dot4(wt2,h2);
            A16[(128 + pt)*AST + o] = (_Float16)fmaxf(z, 0.f);
            #pragma unroll
            for (int k = 0; k < NK; ++k) {
                const float4 g1 = relu4(add4(pf[k], qf));
                A16[(pt*16 + k)*AST + o] = (_Float16)fmaxf(dot4(wsw, g1) + sb2o, 0.f);
            }
        }
    }
    __syncthreads();

    const int lane = t & 63, w = t >> 6;
    const int lr = lane & 15, lg = lane >> 4;
    const int n0w = w * 64;

    f32x4 accG[8][4] = {};
    f32x4 accZ[4] = {};

    #pragma unroll
    for (int kt = 0; kt < 4; ++kt) {
        const int ko = kt*32 + lg*8;
        f16x8 bs[4], bt[4];
        #pragma unroll
        for (int nt = 0; nt < 4; ++nt) {
            const int n = n0w + nt*16 + lr;
            bs[nt] = *(const f16x8*)&ws3h[n*NW + ko];
            bt[nt] = *(const f16x8*)&wt3h[n*NW + ko];
        }
        #pragma unroll
        for (int mt = 0; mt < 8; ++mt) {
            const f16x8 a = *(const f16x8*)&A16[(mt*16 + lr)*AST + ko];
            #pragma unroll
            for (int nt = 0; nt < 4; ++nt)
                accG[mt][nt] = __builtin_amdgcn_mfma_f32_16x16x32_f16(a, bs[nt], accG[mt][nt], 0,0,0);
        }
        const f16x8 az = *(const f16x8*)&A16[(128 + lr)*AST + ko];
        #pragma unroll
        for (int nt = 0; nt < 4; ++nt)
            accZ[nt] = __builtin_amdgcn_mfma_f32_16x16x32_f16(az, bt[nt], accZ[nt], 0,0,0);
    }

    const int rg = lg;
    #pragma unroll
    for (int mt = 0; mt < 8; ++mt) {
        #pragma unroll
        for (int nt = 0; nt < 4; ++nt) {
            float v;
            if (rg < 2)       v = fmaxf(fmaxf(accG[mt][nt][0], accG[mt][nt][1]),
                                        fmaxf(accG[mt][nt][2], accG[mt][nt][3]));
            else if (rg == 2) v = fmaxf(accG[mt][nt][0], accG[mt][nt][1]);
            else              v = -3.0e38f;
            v = fmaxf(v, __shfl_xor(v, 16));
            v = fmaxf(v, __shfl_xor(v, 32));
            if (lane < 16) Ssm[mt][n0w + nt*16 + lane] = v;
        }
    }
    #pragma unroll
    for (int nt = 0; nt < 4; ++nt) {
        #pragma unroll
        for (int q = 0; q < 4; ++q) {
            if (rg < 2) Zr[rg*4 + q][n0w + nt*16 + lr] = accZ[nt][q];
        }
    }
    __syncthreads();

    {
        const int c = t;
        const float tb = tb3[c], sb = sb3[c];
        const size_t go = ((size_t)bb*NC + c)*NPTS + n0;
        const float4 xv0 = *(const float4*)&x[go];
        const float4 xv1 = *(const float4*)&x[go + 4];
        const float xr[8] = {xv0.x,xv0.y,xv0.z,xv0.w, xv1.x,xv1.y,xv1.z,xv1.w};
        float ov[8];
        #pragma unroll
        for (int p = 0; p < 8; ++p)
            ov[p] = fmaxf(Zr[p][c] + tb + Ssm[p][c] + sb + xr[p], 0.f);
        *(float4*)&out[go]     = make_float4(ov[0],ov[1],ov[2],ov[3]);
        *(float4*)&out[go + 4] = make_float4(ov[4],ov[5],ov[6],ov[7]);
    }
}

extern "C" void kernel_launch(void* const* d_in, const int* in_sizes, int n_in,
                              void* d_out, int out_size, void* d_ws, size_t ws_size,
                              hipStream_t stream) {
    (void)in_sizes; (void)n_in; (void)out_size; (void)ws_size;
    const float* x   = (const float*)d_in[0];
    const int*   nb  = (const int*)d_in[2];
    const float* tW1 = (const float*)d_in[3];
    const float* tb1 = (const float*)d_in[4];
    const float* tW2 = (const float*)d_in[5];
    const float* tb2 = (const float*)d_in[6];
    const float* tW3 = (const float*)d_in[7];
    const float* tb3 = (const float*)d_in[8];
    const float* sW1 = (const float*)d_in[9];
    const float* sb1 = (const float*)d_in[10];
    const float* sW2 = (const float*)d_in[11];
    const float* sb2 = (const float*)d_in[12];
    const float* sW3 = (const float*)d_in[13];
    const float* sb3 = (const float*)d_in[14];
    float* out = (float*)d_out;

    float* ws  = (float*)d_ws;
    float* T1r  = ws;                       // 2,048,000 f32
    float* P    = ws + 2048000;             // 2,048,000 f32
    float* Q    = ws + 4096000;             // 2,048,000 f32
    float* xxp  = ws + 6144000;             // 16,000 f32
    int*   tk   = (int*)(ws + 6160000);     // 160,000 int
    float* pval = ws + 6320000;             // 320,000 f32
    int*   pidx = (int*)(ws + 6640000);     // 320,000 int
    _Float16* xb    = (_Float16*)(ws + 6960000);          // 8,388,608 f16
    _Float16* whcat = xb + (size_t)NBATCH * JPAD * 512;   // 98,304 f16
    _Float16* wt3h  = whcat + 384 * 256;                  // 32,768 f16
    _Float16* ws3h  = wt3h + NC * NW;                     // 32,768 f16

    k_prep<<<NBATCH * 32, 256, 0, stream>>>(x, xb, xxp);
    k_wcat<<<384, 256, 0, stream>>>(tW1, sW1, whcat);
    k_wprep<<<32, 256, 0, stream>>>(tW3, wt3h, NC * NW);
    k_wprep<<<32, 256, 0, stream>>>(sW3, ws3h, NC * NW);
    k_rowmm<<<NROWS / 16, 256, 0, stream>>>(xb, whcat, tb1, sb1, T1r, P, Q);
    k_topk<<<512, 256, 0, stream>>>(xb, xxp, pval, pidx);
    k_tkmerge<<<(NROWS + 255) / 256, 256, 0, stream>>>(pval, pidx, tk);
    k_fused<<<NROWS / 8, 256, 0, stream>>>(x, nb, tk, T1r, P, Q,
                                           tW2, tb2, sW2, sb2, wt3h, ws3h, tb3, sb3, out);
}

// Round 12
// 372.434 us; speedup vs baseline: 1.2311x; 1.0545x over previous
//
#include <hip/hip_runtime.h>

#define NPTS 2000
#define NBATCH 8
#define NC 256
#define NW 128
#define NK 10
#define NROWS (NBATCH * NPTS)
#define JPAD 2048

typedef _Float16 f16x8 __attribute__((ext_vector_type(8)));
typedef _Float16 f16x4 __attribute__((ext_vector_type(4)));
typedef float f32x4 __attribute__((ext_vector_type(4)));

__device__ __forceinline__ float dot4(float4 a, float4 b) {
    return a.x*b.x + a.y*b.y + a.z*b.z + a.w*b.w;
}
__device__ __forceinline__ float4 relu4(float4 a) {
    return make_float4(fmaxf(a.x,0.f), fmaxf(a.y,0.f), fmaxf(a.z,0.f), fmaxf(a.w,0.f));
}
__device__ __forceinline__ float4 add4(float4 a, float4 b) {
    return make_float4(a.x+b.x, a.y+b.y, a.z+b.z, a.w+b.w);
}

__device__ __forceinline__ void ins10(float d, int j, float* vals, int* idxs) {
    if (d > vals[9]) {
        float v = d; int id = j;
        #pragma unroll
        for (int s = 0; s < 10; ++s) {
            if (v > vals[s]) {
                float tv = vals[s]; vals[s] = v; v = tv;
                int   ti = idxs[s]; idxs[s] = id; id = ti;
            }
        }
    }
}

__device__ __forceinline__ void gl_lds16(const void* g, void* l) {
    __builtin_amdgcn_global_load_lds(
        (const __attribute__((address_space(1))) void*)g,
        (__attribute__((address_space(3))) void*)l, 16, 0, 0);
}

// ---------------- Kernel P: transpose to kc-major f16 hi/lo (slot-swizzled) + norms ----------------
// xb: [b][kc(8)][row(2048)][8 slots x 16B] f16; slot for h-granule g is g^(row&7),
// for l-granule g is (4+g)^(row&7). One (kc,row) segment = 128 B. Rows >= NPTS zero.
__global__ __launch_bounds__(256) void k_prep(
    const float* __restrict__ x, _Float16* __restrict__ xb,
    float* __restrict__ xx)
{
    __shared__ float T[64][259];
    __shared__ float Pp[64][4];
    const int t  = threadIdx.x;
    const int b  = blockIdx.x >> 5;
    const int n0 = (blockIdx.x & 31) * 64;

    #pragma unroll
    for (int p = 0; p < 64; ++p) {
        const int idx = p*256 + t;
        const int c = idx >> 6, nl = idx & 63;
        T[nl][c] = x[((size_t)b*NC + c)*NPTS + min(n0 + nl, NPTS-1)];
    }
    __syncthreads();

    const int row = t & 63, q = t >> 6;   // q -> kc planes 2q, 2q+1
    const int gr  = n0 + row;
    const bool ok = gr < NPTS;
    const int sx  = gr & 7;
    float ss = 0.f;
    #pragma unroll
    for (int u = 0; u < 2; ++u) {
        const int kc = 2*q + u;
        const size_t base = ((size_t)(b*8 + kc)*JPAD + gr) * 64;
        #pragma unroll
        for (int g = 0; g < 4; ++g) {
            f16x8 vh, vl;
            #pragma unroll
            for (int e = 0; e < 8; ++e) {
                const float f = ok ? T[row][kc*32 + g*8 + e] : 0.f;
                ss = fmaf(f, f, ss);
                const _Float16 h = (_Float16)f;
                vh[e] = h;
                vl[e] = (_Float16)(f - (float)h);
            }
            *(f16x8*)&xb[base + (size_t)((g     ^ sx))*8] = vh;
            *(f16x8*)&xb[base + (size_t)(((4|g) ^ sx))*8] = vl;
        }
    }
    Pp[row][q] = ss;
    __syncthreads();
    if (t < 64 && n0 + t < NPTS)
        xx[(size_t)b*NPTS + n0 + t] = Pp[t][0] + Pp[t][1] + Pp[t][2] + Pp[t][3];
}

// ---------------- Kernel W: f32 -> f16 weight conversion (tW3/sW3) ----------------
__global__ __launch_bounds__(256) void k_wprep(const float* __restrict__ a,
                                               _Float16* __restrict__ o, int n)
{
    const int i = (blockIdx.x*256 + threadIdx.x)*4;
    if (i < n) {
        const float4 v = *(const float4*)&a[i];
        f16x4 h = {(_Float16)v.x, (_Float16)v.y, (_Float16)v.z, (_Float16)v.w};
        *(f16x4*)&o[i] = h;
    }
}

// ---------------- Kernel Wc: build whcat[384][256] f16 = [tW1; sW1_A; sW1_B] ----------------
__global__ __launch_bounds__(256) void k_wcat(
    const float* __restrict__ tW1, const float* __restrict__ sW1,
    _Float16* __restrict__ whcat)
{
    const int idx = blockIdx.x*256 + threadIdx.x;   // 384*256
    const int n = idx >> 8, k = idx & 255;
    float v;
    if (n < 128)      v = tW1[n*256 + k];
    else if (n < 256) v = sW1[(n-128)*512 + k];
    else              v = sW1[(n-256)*512 + 256 + k];
    whcat[idx] = (_Float16)v;
}

// ---------------- Kernel A: MFMA row GEMM -> T1r / P / Q ----------------
__global__ __launch_bounds__(256) void k_rowmm(
    const _Float16* __restrict__ xb, const _Float16* __restrict__ whcat,
    const float* __restrict__ tb1, const float* __restrict__ sb1,
    float* __restrict__ T1r, float* __restrict__ P, float* __restrict__ Q)
{
    const int t = threadIdx.x, lane = t & 63, w = t >> 6;
    const int lr = lane & 15, rg = lane >> 4;
    const int r0 = blockIdx.x * 16;
    const int b  = r0 / NPTS, jr = r0 % NPTS;

    const int row = jr + lr;
    const int sx  = row & 7;
    f16x8 ah[8], al[8];
    #pragma unroll
    for (int kc = 0; kc < 8; ++kc) {
        const size_t base = ((size_t)(b*8 + kc)*JPAD + row) * 64;
        ah[kc] = *(const f16x8*)&xb[base + (size_t)((rg     ^ sx))*8];
        al[kc] = *(const f16x8*)&xb[base + (size_t)(((4|rg) ^ sx))*8];
    }

    #pragma unroll
    for (int nt = 0; nt < 6; ++nt) {
        const int n0 = (w*6 + nt) * 16;
        f32x4 acc = {0.f,0.f,0.f,0.f};
        #pragma unroll
        for (int kc = 0; kc < 8; ++kc) {
            const f16x8 bw = *(const f16x8*)&whcat[(size_t)(n0 + lr)*256 + kc*32 + rg*8];
            acc = __builtin_amdgcn_mfma_f32_16x16x32_f16(ah[kc], bw, acc, 0,0,0);
            acc = __builtin_amdgcn_mfma_f32_16x16x32_f16(al[kc], bw, acc, 0,0,0);
        }
        const int n = n0 + lr;
        float bias; bool dorelu; float* dst;
        if (n < 128)      { bias = tb1[n];     dorelu = true;  dst = T1r + (size_t)r0*NW + n; }
        else if (n < 256) { bias = 0.f;        dorelu = false; dst = P   + (size_t)r0*NW + (n-128); }
        else              { bias = sb1[n-256]; dorelu = false; dst = Q   + (size_t)r0*NW + (n-256); }
        #pragma unroll
        for (int q = 0; q < 4; ++q) {
            float v = acc[q] + bias;
            if (dorelu) v = fmaxf(v, 0.f);
            dst[(size_t)(rg*4 + q)*NW] = v;
        }
    }
}

// ---------------- Kernel B v10: panel GEMM (128i x 128j), DMA dbuf, acc-only regs ----------------
// Grid = 8b x 16ip x 4j4 = 512. Block sweeps 4 j-panels x 8 kc chunks (32 steps, 1 barrier each).
// Per step: stage next (i+j chunks, 2x16KB contiguous DMA), 20 ds_read_b128, 48 MFMA/wave.
// Selection per panel in registers; 4 rg-lists merged in LDS; 4 partials/row.
__global__ __launch_bounds__(256, 2) void k_topk(
    const _Float16* __restrict__ xb, const float* __restrict__ xx,
    float* __restrict__ pval, int* __restrict__ pidx)
{
    __shared__ __align__(16) char smem[65536];   // 2 x (16KB i | 16KB j); merge overlay after

    const int t    = threadIdx.x;
    const int b    = blockIdx.x & 7;             // batch -> XCD
    const int ip   = (blockIdx.x >> 3) & 15;
    const int j4   = blockIdx.x >> 7;            // 0..3
    const int i0   = ip * 128;
    const int lane = t & 63;
    const int w    = t >> 6;
    const int lr   = lane & 15, rg = lane >> 4;
    const char* xbb = (const char*)xb;
    const float* xxb = xx + (size_t)b * NPTS;

    f32x4 acc[2][8] = {};
    float v0[10], v1[10]; int x0[10], x1[10];
    #pragma unroll
    for (int s = 0; s < 10; ++s) { v0[s]=v1[s]=-3.0e38f; x0[s]=x1[s]=0x7fffffff; }

    // prologue: stage step 0 (kc=0, panel 0) into buf 0
    {
        const size_t gbase = (size_t)(b*8 + 0) * JPAD;
        const char* gi = xbb + (gbase + i0) * 128;
        const char* gj = xbb + (gbase + (size_t)(j4*4 + 0)*128) * 128;
        #pragma unroll
        for (int r2 = 0; r2 < 4; ++r2) {
            gl_lds16(gi + t*16 + r2*4096, smem + t*16 + r2*4096);
            gl_lds16(gj + t*16 + r2*4096, smem + 16384 + t*16 + r2*4096);
        }
    }
    __syncthreads();

    for (int step = 0; step < 32; ++step) {
        const int kc = step & 7, buf = step & 1, panel = step >> 3;

        if (step < 31) {   // stage next chunk into buf^1
            const int ns = step + 1, nkc = ns & 7, npan = ns >> 3;
            const size_t gbase = (size_t)(b*8 + nkc) * JPAD;
            const char* gi = xbb + (gbase + i0) * 128;
            const char* gj = xbb + (gbase + (size_t)(j4*4 + npan)*128) * 128;
            char* li = smem + (buf ^ 1)*32768;
            #pragma unroll
            for (int r2 = 0; r2 < 4; ++r2) {
                gl_lds16(gi + t*16 + r2*4096, li + t*16 + r2*4096);
                gl_lds16(gj + t*16 + r2*4096, li + 16384 + t*16 + r2*4096);
            }
        }

        // compute on buf
        {
            const char* IB = smem + buf*32768;
            const char* JB = IB + 16384;
            f16x8 bhf[2], blf[2];
            #pragma unroll
            for (int it = 0; it < 2; ++it) {
                const int il = (w*2 + it)*16 + lr;
                const int sx = il & 7;
                bhf[it] = *(const f16x8*)(IB + il*128 + ((rg     ^ sx))*16);
                blf[it] = *(const f16x8*)(IB + il*128 + (((4|rg) ^ sx))*16);
            }
            #pragma unroll
            for (int jt = 0; jt < 8; ++jt) {
                const int jl = jt*16 + lr;
                const int sx = jl & 7;
                const f16x8 ajh = *(const f16x8*)(JB + jl*128 + ((rg     ^ sx))*16);
                const f16x8 ajl = *(const f16x8*)(JB + jl*128 + (((4|rg) ^ sx))*16);
                #pragma unroll
                for (int it = 0; it < 2; ++it) {
                    acc[it][jt] = __builtin_amdgcn_mfma_f32_16x16x32_f16(ajh, bhf[it], acc[it][jt], 0,0,0);
                    acc[it][jt] = __builtin_amdgcn_mfma_f32_16x16x32_f16(ajh, blf[it], acc[it][jt], 0,0,0);
                    acc[it][jt] = __builtin_amdgcn_mfma_f32_16x16x32_f16(ajl, bhf[it], acc[it][jt], 0,0,0);
                }
            }
        }

        if (kc == 7) {   // selection for this panel (registers + xx only)
            const int jpan = (j4*4 + panel)*128;
            #pragma unroll
            for (int jt = 0; jt < 8; ++jt) {
                const int jg0 = jpan + jt*16 + rg*4;
                const f32x4 xv = *(const f32x4*)&xxb[min(jg0, NPTS-4)];
                {
                    const float d0 = 2.f*acc[0][jt][0] - xv[0];
                    const float d1 = 2.f*acc[0][jt][1] - xv[1];
                    const float d2 = 2.f*acc[0][jt][2] - xv[2];
                    const float d3 = 2.f*acc[0][jt][3] - xv[3];
                    if (fmaxf(fmaxf(d0,d1), fmaxf(d2,d3)) > v0[9]) {
                        if (jg0     < NPTS) ins10(d0, jg0,     v0, x0);
                        if (jg0 + 1 < NPTS) ins10(d1, jg0 + 1, v0, x0);
                        if (jg0 + 2 < NPTS) ins10(d2, jg0 + 2, v0, x0);
                        if (jg0 + 3 < NPTS) ins10(d3, jg0 + 3, v0, x0);
                    }
                    acc[0][jt] = (f32x4){0.f,0.f,0.f,0.f};
                }
                {
                    const float d0 = 2.f*acc[1][jt][0] - xv[0];
                    const float d1 = 2.f*acc[1][jt][1] - xv[1];
                    const float d2 = 2.f*acc[1][jt][2] - xv[2];
                    const float d3 = 2.f*acc[1][jt][3] - xv[3];
                    if (fmaxf(fmaxf(d0,d1), fmaxf(d2,d3)) > v1[9]) {
                        if (jg0     < NPTS) ins10(d0, jg0,     v1, x1);
                        if (jg0 + 1 < NPTS) ins10(d1, jg0 + 1, v1, x1);
                        if (jg0 + 2 < NPTS) ins10(d2, jg0 + 2, v1, x1);
                        if (jg0 + 3 < NPTS) ins10(d3, jg0 + 3, v1, x1);
                    }
                    acc[1][jt] = (f32x4){0.f,0.f,0.f,0.f};
                }
            }
        }
        __syncthreads();
    }

    // ---- in-block merge: 4 rg-lists per i-row (128 groups) ----
    float* mval = (float*)smem;
    int*   midx = (int*)(smem + 20480);
    {
        const int g0 = (w*2 + 0)*16 + lr;
        const int g1 = (w*2 + 1)*16 + lr;
        #pragma unroll
        for (int s = 0; s < 10; ++s) {
            mval[(g0*4 + rg)*10 + s] = v0[s];  midx[(g0*4 + rg)*10 + s] = x0[s];
            mval[(g1*4 + rg)*10 + s] = v1[s];  midx[(g1*4 + rg)*10 + s] = x1[s];
        }
    }
    __syncthreads();
    {   // step 1: 256 workers: merge (g, pr) <- (g, pr)+(g, pr+2)
        const int g = t >> 1, pr = t & 1;
        float* va = &mval[(g*4 + pr)*10];     int* ia = &midx[(g*4 + pr)*10];
        const float* vb = &mval[(g*4 + pr + 2)*10]; const int* ib = &midx[(g*4 + pr + 2)*10];
        float ov[10]; int oi[10]; int pa = 0, pb = 0;
        #pragma unroll
        for (int s = 0; s < 10; ++s) {
            const float A = va[pa], Bv = vb[pb];
            const int  Ai = ia[pa], Bi = ib[pb];
            const bool ta = (A > Bv) || (A == Bv && Ai < Bi);
            ov[s] = ta ? A : Bv; oi[s] = ta ? Ai : Bi;
            pa += ta ? 1 : 0; pb += ta ? 0 : 1;
        }
        #pragma unroll
        for (int s = 0; s < 10; ++s) { va[s] = ov[s]; ia[s] = oi[s]; }
    }
    __syncthreads();
    if (t < 128) {   // step 2: final merge per i + write partial (i, j4)
        const int g = t;
        const int ig = i0 + g;
        if (ig < NPTS) {
            const float* va = &mval[(g*4 + 0)*10]; const int* ia = &midx[(g*4 + 0)*10];
            const float* vb = &mval[(g*4 + 1)*10]; const int* ib = &midx[(g*4 + 1)*10];
            float* ov = &pval[((size_t)(b*NPTS + ig)*4 + j4)*10];
            int*   oi = &pidx[((size_t)(b*NPTS + ig)*4 + j4)*10];
            int pa = 0, pb = 0;
            #pragma unroll
            for (int s = 0; s < 10; ++s) {
                const float A = va[pa], Bv = vb[pb];
                const int  Ai = ia[pa], Bi = ib[pb];
                const bool ta = (A > Bv) || (A == Bv && Ai < Bi);
                ov[s] = ta ? A : Bv; oi[s] = ta ? Ai : Bi;
                pa += ta ? 1 : 0; pb += ta ? 0 : 1;
            }
        }
    }
}

// ---------------- Kernel M: 4-way heads-merge of j-quarter partials ----------------
__global__ __launch_bounds__(256) void k_tkmerge(
    const float* __restrict__ pval, const int* __restrict__ pidx,
    int* __restrict__ tk)
{
    const int r = blockIdx.x*256 + threadIdx.x;
    if (r >= NROWS) return;
    const float* v  = &pval[(size_t)r*40];
    const int*   ix = &pidx[(size_t)r*40];
    const int base = (r / NPTS) * NPTS;
    int* op = &tk[(size_t)r*NK];
    int p0 = 0, p1 = 0, p2 = 0, p3 = 0;
    #pragma unroll
    for (int s = 0; s < NK; ++s) {
        float bv = -3.4e38f; int bi = 0x7fffffff; int bl = 0;
        {
            const float vv = v[p0];       const int ii = ix[p0];
            if (vv > bv || (vv == bv && ii < bi)) { bv = vv; bi = ii; bl = 0; }
        }
        {
            const float vv = v[10 + p1];  const int ii = ix[10 + p1];
            if (vv > bv || (vv == bv && ii < bi)) { bv = vv; bi = ii; bl = 1; }
        }
        {
            const float vv = v[20 + p2];  const int ii = ix[20 + p2];
            if (vv > bv || (vv == bv && ii < bi)) { bv = vv; bi = ii; bl = 2; }
        }
        {
            const float vv = v[30 + p3];  const int ii = ix[30 + p3];
            if (vv > bv || (vv == bv && ii < bi)) { bv = vv; bi = ii; bl = 3; }
        }
        p0 += (bl == 0); p1 += (bl == 1); p2 += (bl == 2); p3 += (bl == 3);
        op[s] = base + bi;
    }
}

// ---------------- Kernel D: fused tail (MFMA phase 2, unchanged) ----------------
#define AST 136
__global__ __launch_bounds__(256, 2) void k_fused(
    const float* __restrict__ x,
    const int* __restrict__ nb, const int* __restrict__ tk,
    const float* __restrict__ T1r, const float* __restrict__ P, const float* __restrict__ Q,
    const float* __restrict__ tW2, const float* __restrict__ tb2,
    const float* __restrict__ sW2, const float* __restrict__ sb2,
    const _Float16* __restrict__ wt3h, const _Float16* __restrict__ ws3h,
    const float* __restrict__ tb3, const float* __restrict__ sb3,
    float* __restrict__ out)
{
    __shared__ __align__(16) _Float16 A16[144*AST];
    __shared__ float Ssm[8][260];
    __shared__ float Zr[8][260];

    const int t  = threadIdx.x;
    const int r0 = blockIdx.x * 8;
    const int bb = r0 / NPTS;
    const int n0 = r0 % NPTS;

    {
        const float4 z4 = make_float4(0.f,0.f,0.f,0.f);
        float4* p4 = (float4*)A16;
        #pragma unroll
        for (int i = 0; i < 10; ++i) {
            const int idx = t + i*256;
            if (idx < 2448) p4[idx] = z4;
        }
    }
    __syncthreads();

    {
        const int o    = t & 127;
        const int half = t >> 7;
        const int g4   = o & ~3;

        const float4 f0 = *(const float4*)&tW2[o*12];
        const float4 f1 = *(const float4*)&tW2[o*12 + 4];
        const float4 f2 = *(const float4*)&tW2[o*12 + 8];
        const float4 wt0 = make_float4(f0.x, f0.w, f1.z, f2.y);
        const float4 wt1 = make_float4(f0.y, f1.x, f1.w, f2.z);
        const float4 wt2 = make_float4(f0.z, f1.y, f2.x, f2.w);
        const float4 wsw = *(const float4*)&sW2[o*4];
        const float tb2o = tb2[o], sb2o = sb2[o];

        #pragma unroll
        for (int ptl = 0; ptl < 4; ++ptl) {
            const int pt = half*4 + ptl;
            const int r  = r0 + pt;
            const int nb0 = nb[r*3+0], nb1 = nb[r*3+1], nb2 = nb[r*3+2];
            int ki[NK];
            #pragma unroll
            for (int k = 0; k < NK; ++k) ki[k] = tk[r*NK + k];
            const float4 h0 = *(const float4*)&T1r[(size_t)nb0*NW + g4];
            const float4 h1 = *(const float4*)&T1r[(size_t)nb1*NW + g4];
            const float4 h2 = *(const float4*)&T1r[(size_t)nb2*NW + g4];
            const float4 qf = *(const float4*)&Q[(size_t)r*NW + g4];
            float4 pf[NK];
            #pragma unroll
            for (int k = 0; k < NK; ++k) pf[k] = *(const float4*)&P[(size_t)ki[k]*NW + g4];

            const float z = tb2o + dot4(wt0,h0) + dot4(wt1,h1) + dot4(wt2,h2);
            A16[(128 + pt)*AST + o] = (_Float16)fmaxf(z, 0.f);
            #pragma unroll
            for (int k = 0; k < NK; ++k) {
                const float4 g1 = relu4(add4(pf[k], qf));
                A16[(pt*16 + k)*AST + o] = (_Float16)fmaxf(dot4(wsw, g1) + sb2o, 0.f);
            }
        }
    }
    __syncthreads();

    const int lane = t & 63, w = t >> 6;
    const int lr = lane & 15, lg = lane >> 4;
    const int n0w = w * 64;

    f32x4 accG[8][4] = {};
    f32x4 accZ[4] = {};

    #pragma unroll
    for (int kt = 0; kt < 4; ++kt) {
        const int ko = kt*32 + lg*8;
        f16x8 bs[4], bt[4];
        #pragma unroll
        for (int nt = 0; nt < 4; ++nt) {
            const int n = n0w + nt*16 + lr;
            bs[nt] = *(const f16x8*)&ws3h[n*NW + ko];
            bt[nt] = *(const f16x8*)&wt3h[n*NW + ko];
        }
        #pragma unroll
        for (int mt = 0; mt < 8; ++mt) {
            const f16x8 a = *(const f16x8*)&A16[(mt*16 + lr)*AST + ko];
            #pragma unroll
            for (int nt = 0; nt < 4; ++nt)
                accG[mt][nt] = __builtin_amdgcn_mfma_f32_16x16x32_f16(a, bs[nt], accG[mt][nt], 0,0,0);
        }
        const f16x8 az = *(const f16x8*)&A16[(128 + lr)*AST + ko];
        #pragma unroll
        for (int nt = 0; nt < 4; ++nt)
            accZ[nt] = __builtin_amdgcn_mfma_f32_16x16x32_f16(az, bt[nt], accZ[nt], 0,0,0);
    }

    const int rg = lg;
    #pragma unroll
    for (int mt = 0; mt < 8; ++mt) {
        #pragma unroll
        for (int nt = 0; nt < 4; ++nt) {
            float v;
            if (rg < 2)       v = fmaxf(fmaxf(accG[mt][nt][0], accG[mt][nt][1]),
                                        fmaxf(accG[mt][nt][2], accG[mt][nt][3]));
            else if (rg == 2) v = fmaxf(accG[mt][nt][0], accG[mt][nt][1]);
            else              v = -3.0e38f;
            v = fmaxf(v, __shfl_xor(v, 16));
            v = fmaxf(v, __shfl_xor(v, 32));
            if (lane < 16) Ssm[mt][n0w + nt*16 + lane] = v;
        }
    }
    #pragma unroll
    for (int nt = 0; nt < 4; ++nt) {
        #pragma unroll
        for (int q = 0; q < 4; ++q) {
            if (rg < 2) Zr[rg*4 + q][n0w + nt*16 + lr] = accZ[nt][q];
        }
    }
    __syncthreads();

    {
        const int c = t;
        const float tb = tb3[c], sb = sb3[c];
        const size_t go = ((size_t)bb*NC + c)*NPTS + n0;
        const float4 xv0 = *(const float4*)&x[go];
        const float4 xv1 = *(const float4*)&x[go + 4];
        const float xr[8] = {xv0.x,xv0.y,xv0.z,xv0.w, xv1.x,xv1.y,xv1.z,xv1.w};
        float ov[8];
        #pragma unroll
        for (int p = 0; p < 8; ++p)
            ov[p] = fmaxf(Zr[p][c] + tb + Ssm[p][c] + sb + xr[p], 0.f);
        *(float4*)&out[go]     = make_float4(ov[0],ov[1],ov[2],ov[3]);
        *(float4*)&out[go + 4] = make_float4(ov[4],ov[5],ov[6],ov[7]);
    }
}

extern "C" void kernel_launch(void* const* d_in, const int* in_sizes, int n_in,
                              void* d_out, int out_size, void* d_ws, size_t ws_size,
                              hipStream_t stream) {
    (void)in_sizes; (void)n_in; (void)out_size; (void)ws_size;
    const float* x   = (const float*)d_in[0];
    const int*   nb  = (const int*)d_in[2];
    const float* tW1 = (const float*)d_in[3];
    const float* tb1 = (const float*)d_in[4];
    const float* tW2 = (const float*)d_in[5];
    const float* tb2 = (const float*)d_in[6];
    const float* tW3 = (const float*)d_in[7];
    const float* tb3 = (const float*)d_in[8];
    const float* sW1 = (const float*)d_in[9];
    const float* sb1 = (const float*)d_in[10];
    const float* sW2 = (const float*)d_in[11];
    const float* sb2 = (const float*)d_in[12];
    const float* sW3 = (const float*)d_in[13];
    const float* sb3 = (const float*)d_in[14];
    float* out = (float*)d_out;

    float* ws  = (float*)d_ws;
    float* T1r  = ws;                       // 2,048,000 f32
    float* P    = ws + 2048000;             // 2,048,000 f32
    float* Q    = ws + 4096000;             // 2,048,000 f32
    float* xxp  = ws + 6144000;             // 16,000 f32
    int*   tk   = (int*)(ws + 6160000);     // 160,000 int
    float* pval = ws + 6320000;             // 640,000 f32
    int*   pidx = (int*)(ws + 6960000);     // 640,000 int
    _Float16* xb    = (_Float16*)(ws + 7600000);          // 8,388,608 f16
    _Float16* whcat = xb + (size_t)NBATCH * 8 * JPAD * 64;
    _Float16* wt3h  = whcat + 384 * 256;
    _Float16* ws3h  = wt3h + NC * NW;

    k_prep<<<NBATCH * 32, 256, 0, stream>>>(x, xb, xxp);
    k_wcat<<<384, 256, 0, stream>>>(tW1, sW1, whcat);
    k_wprep<<<32, 256, 0, stream>>>(tW3, wt3h, NC * NW);
    k_wprep<<<32, 256, 0, stream>>>(sW3, ws3h, NC * NW);
    k_rowmm<<<NROWS / 16, 256, 0, stream>>>(xb, whcat, tb1, sb1, T1r, P, Q);
    k_topk<<<512, 256, 0, stream>>>(xb, xxp, pval, pidx);
    k_tkmerge<<<(NROWS + 255) / 256, 256, 0, stream>>>(pval, pidx, tk);
    k_fused<<<NROWS / 8, 256, 0, stream>>>(x, nb, tk, T1r, P, Q,
                                           tW2, tb2, sW2, sb2, wt3h, ws3h, tb3, sb3, out);
}